// Round 9
// baseline (334.680 us; speedup 1.0000x reference)
//
#include <hip/hip_runtime.h>
#include <float.h>

// Problem constants
#define N_PTS    32768       // 8*16*16*16 spatial positions
#define N_CODES  2048
#define DIM      256
#define S_STRIDE 4096        // d*h*w stride of channel dim in z (floats)
#define B_STRIDE 1048576     // per-batch stride in z (256*4096 floats)
#define N_ELEM   8388608     // total z elements

#define MARGIN   8e-4f       // >= 2x |screen-score - np-score| bound (validated R5-R8)

// ws layout (bytes), 512-aligned
#define WS_PARTIAL 0          // float[64]
#define WS_E2      512        // float[2048]             -> 8704
#define WS_EB      8704       // bf16[2048*256] 1 MB     -> 1057280
#define WS_ZT      1057280    // bf16[32768*256] 16.8 MB -> 17834496
#define WS_TMIN    17834496   // float[32768*128] 16.8MB -> 34611712

typedef unsigned short ushort_t;
typedef short bf16x8 __attribute__((ext_vector_type(8)));
typedef float f32x4 __attribute__((ext_vector_type(4)));

__device__ __forceinline__ ushort_t f2bf(float v) {   // RNE fp32->bf16 (no NaN in data)
    const unsigned u = __float_as_uint(v);
    return (ushort_t)((u + 0x7FFFu + ((u >> 16) & 1u)) >> 16);
}

__device__ __forceinline__ void async_copy16(void* lds, const void* g) {
    __builtin_amdgcn_global_load_lds(
        (const __attribute__((address_space(1))) unsigned int*)g,
        (__attribute__((address_space(3))) unsigned int*)lds, 16, 0, 0);
}

// emb fp32 [k][256] -> bf16 eb [k][256] (coalesced)
__global__ void conv_emb_kernel(const float* __restrict__ emb, ushort_t* __restrict__ eb) {
    const int gid = blockIdx.x * 256 + threadIdx.x;   // 512 blocks: 2048 codes x 64 float4
    const int k = gid >> 6, c4 = gid & 63;
    const float4 u = *reinterpret_cast<const float4*>(emb + (size_t)k * DIM + c4 * 4);
    ushort4 v; v.x = f2bf(u.x); v.y = f2bf(u.y); v.z = f2bf(u.z); v.w = f2bf(u.w);
    *reinterpret_cast<ushort4*>(eb + (size_t)k * DIM + c4 * 4) = v;
}

// e2[k] = np-pairwise sum of emb[k][:]^2; also zeroes loss partials.
__global__ void e2p_kernel(const float* __restrict__ emb, float* __restrict__ e2,
                           float* __restrict__ partial) {
    const int k = blockIdx.x * 256 + threadIdx.x;
    if (blockIdx.x == 0 && threadIdx.x < 64) partial[threadIdx.x] = 0.f;
    const float* base = emb + (size_t)k * DIM;
    float half[2];
    #pragma unroll
    for (int h = 0; h < 2; ++h) {
        float r[8];
        #pragma unroll
        for (int j = 0; j < 8; ++j) { const float v = base[h * 128 + j]; r[j] = __fmul_rn(v, v); }
        for (int t = 8; t < 128; t += 8)
            #pragma unroll
            for (int j = 0; j < 8; ++j) {
                const float v = base[h * 128 + t + j];
                r[j] = __fadd_rn(r[j], __fmul_rn(v, v));
            }
        half[h] = __fadd_rn(__fadd_rn(__fadd_rn(r[0], r[1]), __fadd_rn(r[2], r[3])),
                            __fadd_rn(__fadd_rn(r[4], r[5]), __fadd_rn(r[6], r[7])));
    }
    e2[k] = __fadd_rn(half[0], half[1]);
}

// z [8][256][4096] fp32 -> z_t [n][c] bf16 (pitch 256), 64x64 LDS transpose tiles.
__global__ void transpose_kernel(const float* __restrict__ z, ushort_t* __restrict__ zt) {
    __shared__ ushort_t lt[64][72];
    const int bx = blockIdx.x;            // 2048 = 8 b x 4 cg x 64 sg
    const int b = bx >> 8, cg = (bx >> 6) & 3, sg = bx & 63;
    const int c0 = cg * 64, s0 = sg * 64;
    const int t = threadIdx.x;
    {
        const int cl = t >> 4, s4 = t & 15;
        #pragma unroll
        for (int j = 0; j < 4; ++j) {
            const int c = cl + 16 * j;
            const float4 u = *reinterpret_cast<const float4*>(
                z + (size_t)b * B_STRIDE + (size_t)(c0 + c) * S_STRIDE + s0 + s4 * 4);
            ushort4 v; v.x = f2bf(u.x); v.y = f2bf(u.y); v.z = f2bf(u.z); v.w = f2bf(u.w);
            *reinterpret_cast<ushort4*>(&lt[c][s4 * 4]) = v;
        }
    }
    __syncthreads();
    {
        const int sl = t >> 4, c4 = t & 15;
        #pragma unroll
        for (int j = 0; j < 4; ++j) {
            const int s = sl + 16 * j;
            ushort4 v;
            v.x = lt[c4 * 4 + 0][s]; v.y = lt[c4 * 4 + 1][s];
            v.z = lt[c4 * 4 + 2][s]; v.w = lt[c4 * 4 + 3][s];
            *reinterpret_cast<ushort4*>(zt + (size_t)(b * 4096 + s0 + s) * DIM + c0 + c4 * 4) = v;
        }
    }
}

// m97-style screen GEMM: BM=128 pts, BN=256 codes, BK=64, single 48 KB buffer,
// 2-barrier K-loop, global_load_lds staging with XOR chunk swizzle, 8x4 wave tile.
// Emits per-(point, 16-code-group) min of s~ = e2[k] - 2*dot_bf16 -> tmin[n][128].
__global__ __launch_bounds__(256, 3) void screen_kernel(
    const ushort_t* __restrict__ zt, const ushort_t* __restrict__ eb,
    const float* __restrict__ e2, float* __restrict__ tmin)
{
    __shared__ char lds[49152];          // A: [0,16K) = 128 rows x 8 chunks; B: [16K,48K) = 256 x 8
    __shared__ float e2s[256];
    const int tid = threadIdx.x;
    const int bm = blockIdx.x & 255, bn = blockIdx.x >> 8;   // bm fast -> eb tile L2-hot
    const int n0 = bm * 128, k0 = bn * 256;
    e2s[tid] = e2[k0 + tid];
    const int wv = tid >> 6, lane = tid & 63;
    const int col = lane & 15, quad = lane >> 4;
    const int cswz = col & 7;

    f32x4 acc[8][4];
    #pragma unroll
    for (int i = 0; i < 8; ++i)
        #pragma unroll
        for (int j = 0; j < 4; ++j) acc[i][j] = (f32x4){0.f, 0.f, 0.f, 0.f};

    for (int kc = 0; kc < 4; ++kc) {
        __syncthreads();                 // prior-iter LDS reads done before overwrite
        #pragma unroll
        for (int it = 0; it < 12; ++it) {    // 3072 x 16B chunks: A 1024, B 2048
            const int L = tid + it * 256;
            if (L < 1024) {
                const int row = L >> 3, pc = L & 7, c = pc ^ (row & 7);
                async_copy16(lds + L * 16,
                             zt + ((size_t)(n0 + row) * DIM + kc * 64 + c * 8));
            } else {
                const int L2 = L - 1024;
                const int row = L2 >> 3, pc = L2 & 7, c = pc ^ (row & 7);
                async_copy16(lds + 16384 + L2 * 16,
                             eb + ((size_t)(k0 + row) * DIM + kc * 64 + c * 8));
            }
        }
        __syncthreads();                 // drains vmcnt: staged data visible
        #pragma unroll
        for (int s = 0; s < 2; ++s) {
            const int pc = (s * 4 + quad) ^ cswz;
            bf16x8 bq[4];
            #pragma unroll
            for (int j = 0; j < 4; ++j) {
                const int brow = wv * 64 + j * 16 + col;
                bq[j] = *reinterpret_cast<const bf16x8*>(lds + 16384 + (brow * 8 + pc) * 16);
            }
            #pragma unroll
            for (int i = 0; i < 8; ++i) {
                const int arow = i * 16 + col;
                const bf16x8 af = *reinterpret_cast<const bf16x8*>(lds + (arow * 8 + pc) * 16);
                #pragma unroll
                for (int j = 0; j < 4; ++j)
                    acc[i][j] = __builtin_amdgcn_mfma_f32_16x16x32_bf16(af, bq[j], acc[i][j], 0, 0, 0);
            }
        }
    }
    // epilogue: per-16-code-group minima (reduce across the 16 col lanes)
    #pragma unroll
    for (int i = 0; i < 8; ++i) {
        #pragma unroll
        for (int j = 0; j < 4; ++j) {
            const float e2v = e2s[wv * 64 + j * 16 + col];
            float tm[4];
            #pragma unroll
            for (int r = 0; r < 4; ++r) tm[r] = fmaf(-2.f, acc[i][j][r], e2v);
            #pragma unroll
            for (int off = 1; off < 16; off <<= 1)
                #pragma unroll
                for (int r = 0; r < 4; ++r) tm[r] = fminf(tm[r], __shfl_xor(tm[r], off));
            if (col == 0) {
                const int g = bn * 16 + wv * 4 + j;     // 16-code group index, 128 total
                const int nb = n0 + i * 16 + quad * 4;  // C/D row = quad*4+r
                #pragma unroll
                for (int r = 0; r < 4; ++r) tmin[(size_t)(nb + r) * 128 + g] = tm[r];
            }
        }
    }
}

// Fused exact re-resolve + z2 + gather + loss.  Block: 16 points (small LDS ->
// ~5 blocks/CU so serial np-exact chains overlap across waves).  Each wave owns
// 4 points with tmin prefetched up front.
__global__ __launch_bounds__(256, 4) void exact_kernel(
    const float* __restrict__ z, const float* __restrict__ emb,
    const float* __restrict__ e2, const float* __restrict__ tmin,
    float* __restrict__ outf, float* __restrict__ out_idx, float* __restrict__ partial)
{
    __shared__ float zs[16 * 260];       // [p][c] pitch 260, 16.6 KB
    const int tid = threadIdx.x;
    const int n0 = blockIdx.x * 16;
    const int b = n0 >> 12, s0 = n0 & 4095;
    {   // coalesced stage: 4 lanes x float4 = one 64B line per channel
        const int tq = tid & 3, cg = tid >> 2;   // cg in [0,64)
        #pragma unroll
        for (int j = 0; j < 4; ++j) {
            const int c = cg + 64 * j;
            const float4 u = *reinterpret_cast<const float4*>(
                z + (size_t)b * B_STRIDE + (size_t)c * S_STRIDE + s0 + tq * 4);
            zs[(tq * 4 + 0) * 260 + c] = u.x;
            zs[(tq * 4 + 1) * 260 + c] = u.y;
            zs[(tq * 4 + 2) * 260 + c] = u.z;
            zs[(tq * 4 + 3) * 260 + c] = u.w;
        }
    }
    __syncthreads();
    const int wv = tid >> 6, lane = tid & 63;
    // prefetch tmin rows for this wave's 4 points (batched -> one latency)
    float a0[4], a1[4];
    #pragma unroll
    for (int pp = 0; pp < 4; ++pp) {
        const size_t nb = (size_t)(n0 + wv * 4 + pp) * 128;
        a0[pp] = tmin[nb + lane];
        a1[pp] = tmin[nb + 64 + lane];
    }
    float lossacc = 0.f;
    #pragma unroll 1
    for (int pp = 0; pp < 4; ++pp) {
        const int p = wv * 4 + pp;
        const int n = n0 + p;
        const float* zr = &zs[p * 260];
        // np-exact z2: 16 lanes run the 8-accumulator chains, xor-tree combine in np order
        float r = 0.f;
        if (lane < 16) {
            const int h = lane >> 3, j = lane & 7;
            float v = zr[h * 128 + j];
            r = __fmul_rn(v, v);
            #pragma unroll
            for (int t = 1; t < 16; ++t) {
                v = zr[h * 128 + j + 8 * t];
                r = __fadd_rn(r, __fmul_rn(v, v));
            }
        }
        { float v = __shfl_xor(r, 1); r = __fadd_rn(r, v); }
        { float v = __shfl_xor(r, 2); r = __fadd_rn(r, v); }
        { float v = __shfl_xor(r, 4); r = __fadd_rn(r, v); }
        const float z2n = __fadd_rn(__shfl(r, 0), __shfl(r, 8));
        // threshold over 128 group minima
        float mn = fminf(a0[pp], a1[pp]);
        #pragma unroll
        for (int off = 1; off < 64; off <<= 1) mn = fminf(mn, __shfl_xor(mn, off));
        const float thr = mn + MARGIN;
        unsigned long long M0 = __ballot(a0[pp] <= thr);
        unsigned long long M1 = __ballot(a1[pp] <= thr);
        float bs = FLT_MAX; int bk = 0x7FFFFFFF;
        while (M0 | M1) {
            int sel[4];
            #pragma unroll
            for (int sl = 0; sl < 4; ++sl) {          // wave-uniform extraction of <=4 groups
                int v = -1;
                if (M0) { v = __ffsll(M0) - 1; M0 &= M0 - 1; }
                else if (M1) { v = 64 + __ffsll(M1) - 1; M1 &= M1 - 1; }
                sel[sl] = v;
            }
            const int myt = sel[lane >> 4];
            if (myt >= 0) {
                const int kg = myt * 16 + (lane & 15);
                const float* er = emb + (size_t)kg * DIM;
                const float e2k = e2[kg];              // hoistable: no chain dependency
                float dot = 0.f;                       // np-exact ascending-c fmaf chain
                #pragma unroll 8
                for (int c4 = 0; c4 < 64; ++c4) {
                    const float4 ev = reinterpret_cast<const float4*>(er)[c4];
                    const float4 zv = *reinterpret_cast<const float4*>(zr + c4 * 4);  // broadcast
                    dot = fmaf(zv.x, ev.x, dot);
                    dot = fmaf(zv.y, ev.y, dot);
                    dot = fmaf(zv.z, ev.z, dot);
                    dot = fmaf(zv.w, ev.w, dot);
                }
                const float A = __fadd_rn(z2n, e2k);
                const float s = __fsub_rn(A, __fmul_rn(2.f, dot));
                if (s < bs || (s == bs && kg < bk)) { bs = s; bk = kg; }
            }
        }
        #pragma unroll
        for (int off = 1; off < 64; off <<= 1) {   // lex-min (s,k) = np.argmin
            const float os = __shfl_xor(bs, off);
            const int ok = __shfl_xor(bk, off);
            if (os < bs || (os == bs && ok < bk)) { bs = os; bk = ok; }
        }
        // gather z_q row (out[n][c] = emb[idx[n]][c]) + loss, stride-64 scalar (coalesced)
        const float* eq = emb + (size_t)bk * DIM;
        float* op = outf + (size_t)n * DIM;
        #pragma unroll
        for (int j = 0; j < 4; ++j) {
            const int c = lane + 64 * j;
            const float q = eq[c];
            op[c] = q;
            const float d = q - zr[c];
            lossacc = fmaf(d, d, lossacc);
        }
        if (lane == 0) out_idx[n] = (float)bk;
    }
    #pragma unroll
    for (int off = 1; off < 64; off <<= 1) lossacc += __shfl_xor(lossacc, off);
    if (lane == 0) atomicAdd(&partial[blockIdx.x & 63], lossacc);
}

__global__ void finalize_kernel(const float* __restrict__ partial, float* __restrict__ out_loss) {
    float v = partial[threadIdx.x];          // 64 threads
    #pragma unroll
    for (int off = 1; off < 64; off <<= 1) v += __shfl_xor(v, off);
    if (threadIdx.x == 0)
        *out_loss = v * 1.25f / (float)N_ELEM;   // (1+BETA)*mean
}

extern "C" void kernel_launch(void* const* d_in, const int* in_sizes, int n_in,
                              void* d_out, int out_size, void* d_ws, size_t ws_size,
                              hipStream_t stream) {
    const float* z = (const float*)d_in[0];
    const float* emb = (const float*)d_in[1];
    char* ws = (char*)d_ws;
    float* partial = (float*)(ws + WS_PARTIAL);
    float* e2 = (float*)(ws + WS_E2);
    ushort_t* eb = (ushort_t*)(ws + WS_EB);
    ushort_t* zt = (ushort_t*)(ws + WS_ZT);
    float* tmin = (float*)(ws + WS_TMIN);
    float* outf = (float*)d_out;
    float* out_loss = outf + N_ELEM;
    float* out_idx = outf + N_ELEM + 1;

    conv_emb_kernel<<<512, 256, 0, stream>>>(emb, eb);
    e2p_kernel<<<N_CODES / 256, 256, 0, stream>>>(emb, e2, partial);
    transpose_kernel<<<2048, 256, 0, stream>>>(z, zt);
    screen_kernel<<<2048, 256, 0, stream>>>(zt, eb, e2, tmin);
    exact_kernel<<<N_PTS / 16, 256, 0, stream>>>(z, emb, e2, tmin, outf, out_idx, partial);
    finalize_kernel<<<1, 64, 0, stream>>>(partial, out_loss);
}